// Round 1
// baseline (41705.853 us; speedup 1.0000x reference)
//
#include <hip/hip_runtime.h>
#include <hip/hip_cooperative_groups.h>

namespace cg = cooperative_groups;

#define TSTEPS 512
#define BSZ 256
#define HCH 256

// Grid: 256 blocks = 16 btile (batch groups of 16 rows) x 16 jtile (hc groups of 16).
// Block: 256 threads: b = tid>>4 (row within tile), jj = tid&15 (hc within tile).
// Each thread owns one (row, hc) cell: keeps h,c,u,du,skip in registers
// (scalars replicated across the 16 jtile blocks / 16 jj threads of a row —
// identical deterministic updates, so no cross-block scalar traffic).
// One grid.sync per time step:
//   PhaseA: gates GEMM (W in LDS, A=[x_t|h] from global), cell update,
//           du partial (double) -> part[], new h -> hbuf[parity].
//   sync
//   PhaseB: sum 16 partials in fixed order -> du_n, scalar skip-state update,
//           write seq_out[t]  (after sync => layer-1 in-place input is safe).
template<int IC>
__global__ __launch_bounds__(256)
void skiplstm_layer(const float* __restrict__ x,      // (T, BS, IC)
                    const float* __restrict__ Wih,    // (4H, IC)
                    const float* __restrict__ Whh,    // (4H, H)
                    const float* __restrict__ bih,    // (4H)
                    const float* __restrict__ bhh,    // (4H)
                    const float* __restrict__ lw,     // (H)
                    const float* __restrict__ lb,     // (1)
                    float* __restrict__ seq_out,      // (T, BS, H)
                    float* __restrict__ hs_out,       // (BS, H)
                    float* __restrict__ cs_out,       // (BS, H)
                    float* __restrict__ hbuf,         // 2*BS*H floats (ws)
                    double* __restrict__ part,        // 2*16*BS doubles (ws)
                    float* __restrict__ skipdu,       // 2*BS floats (ws): [du | skip]
                    int first_layer)
{
    constexpr int KH = IC + HCH;          // fused K: [x | h]
    constexpr int KPAD = KH + 4;          // +4 floats: LDS bank de-conflict
    __shared__ float Wl[64][KPAD];        // this block's 64 gate-cols, all K

    const int tid   = threadIdx.x;
    const int bid   = blockIdx.x;
    const int btile = bid >> 4;
    const int jtile = bid & 15;
    const int brow  = btile * 16 + (tid >> 4);
    const int jj    = tid & 15;
    const int J     = jtile * 16 + jj;

    // ---- one-time: stage W slice into LDS (coalesced over k) ----
    for (int col = 0; col < 64; ++col) {
        const int grow = (col >> 4) * HCH + jtile * 16 + (col & 15);
        const float* __restrict__ wsrc = Wih + (size_t)grow * IC;
        for (int k = tid; k < IC; k += 256) Wl[col][k] = wsrc[k];
        const float* __restrict__ hsrc = Whh + (size_t)grow * HCH;
        for (int k = tid; k < HCH; k += 256) Wl[col][IC + k] = hsrc[k];
    }

    const float bias0 = bih[0*HCH + J] + bhh[0*HCH + J];
    const float bias1 = bih[1*HCH + J] + bhh[1*HCH + J];
    const float bias2 = bih[2*HCH + J] + bhh[2*HCH + J];
    const float bias3 = bih[3*HCH + J] + bhh[3*HCH + J];
    const float lwv = lw[J];
    const float lbv = lb[0];

    float h_reg = 0.f, c_reg = 0.f, u_reg = 1.f;
    float du_reg;
    int   skip_reg;
    if (first_layer) { du_reg = 0.f; skip_reg = 0; }
    else {
        du_reg   = skipdu[brow];
        skip_reg = (skipdu[BSZ + brow] > 0.5f) ? 1 : 0;
    }

    // h(-1) = 0 lives in parity-1 buffer (read at t=0)
    hbuf[(size_t)1 * BSZ * HCH + (size_t)brow * HCH + J] = 0.f;

    cg::grid_group grid = cg::this_grid();
    grid.sync();   // Wl visible in-block, zeros + skipdu visible grid-wide

    const float* __restrict__ wp0 = &Wl[0*16 + jj][0];
    const float* __restrict__ wp1 = &Wl[1*16 + jj][0];
    const float* __restrict__ wp2 = &Wl[2*16 + jj][0];
    const float* __restrict__ wp3 = &Wl[3*16 + jj][0];

    for (int t = 0; t < TSTEPS; ++t) {
        const int   par = t & 1;
        const float bu  = rintf(u_reg);            // jnp.round == rint (half-even)

        float acc0 = bias0, acc1 = bias1, acc2 = bias2, acc3 = bias3;
        if (!skip_reg) {   // skipped rows never use the cell output -> skip GEMM
            const float* __restrict__ ax = x + ((size_t)t * BSZ + brow) * IC;
            #pragma unroll 4
            for (int k = 0; k < IC; k += 4) {
                const float4 a  = *(const float4*)(ax + k);
                const float4 w0 = *(const float4*)(wp0 + k);
                const float4 w1 = *(const float4*)(wp1 + k);
                const float4 w2 = *(const float4*)(wp2 + k);
                const float4 w3 = *(const float4*)(wp3 + k);
                acc0 = fmaf(a.x, w0.x, acc0); acc0 = fmaf(a.y, w0.y, acc0);
                acc0 = fmaf(a.z, w0.z, acc0); acc0 = fmaf(a.w, w0.w, acc0);
                acc1 = fmaf(a.x, w1.x, acc1); acc1 = fmaf(a.y, w1.y, acc1);
                acc1 = fmaf(a.z, w1.z, acc1); acc1 = fmaf(a.w, w1.w, acc1);
                acc2 = fmaf(a.x, w2.x, acc2); acc2 = fmaf(a.y, w2.y, acc2);
                acc2 = fmaf(a.z, w2.z, acc2); acc2 = fmaf(a.w, w2.w, acc2);
                acc3 = fmaf(a.x, w3.x, acc3); acc3 = fmaf(a.y, w3.y, acc3);
                acc3 = fmaf(a.z, w3.z, acc3); acc3 = fmaf(a.w, w3.w, acc3);
            }
            const float* __restrict__ ah =
                hbuf + (size_t)(1 - par) * BSZ * HCH + (size_t)brow * HCH;
            #pragma unroll 4
            for (int k = 0; k < HCH; k += 4) {
                const float4 a  = *(const float4*)(ah + k);
                const float4 w0 = *(const float4*)(wp0 + IC + k);
                const float4 w1 = *(const float4*)(wp1 + IC + k);
                const float4 w2 = *(const float4*)(wp2 + IC + k);
                const float4 w3 = *(const float4*)(wp3 + IC + k);
                acc0 = fmaf(a.x, w0.x, acc0); acc0 = fmaf(a.y, w0.y, acc0);
                acc0 = fmaf(a.z, w0.z, acc0); acc0 = fmaf(a.w, w0.w, acc0);
                acc1 = fmaf(a.x, w1.x, acc1); acc1 = fmaf(a.y, w1.y, acc1);
                acc1 = fmaf(a.z, w1.z, acc1); acc1 = fmaf(a.w, w1.w, acc1);
                acc2 = fmaf(a.x, w2.x, acc2); acc2 = fmaf(a.y, w2.y, acc2);
                acc2 = fmaf(a.z, w2.z, acc2); acc2 = fmaf(a.w, w2.w, acc2);
                acc3 = fmaf(a.x, w3.x, acc3); acc3 = fmaf(a.y, w3.y, acc3);
                acc3 = fmaf(a.z, w3.z, acc3); acc3 = fmaf(a.w, w3.w, acc3);
            }
        }

        // ---- cell + gating (values for skipped rows are computed-but-discarded,
        //      exactly like the reference's jnp.where) ----
        const float si = 1.f / (1.f + expf(-acc0));
        const float sf = 1.f / (1.f + expf(-acc1));
        const float tg = tanhf(acc2);
        const float so = 1.f / (1.f + expf(-acc3));
        const float cc = sf * c_reg + si * tg;
        const float ch = so * tanhf(cc);
        const float nc_n = cc * bu;
        const float nh_n = ch * bu;

        // du partial over this block's 16 hc (double, deterministic)
        double p = (double)nc_n * (double)lwv;
        p += __shfl_xor(p, 1);
        p += __shfl_xor(p, 2);
        p += __shfl_xor(p, 4);
        p += __shfl_xor(p, 8);
        if (jj == 0) part[(size_t)par * 16 * BSZ + (size_t)jtile * BSZ + brow] = p;

        const float nh = skip_reg ? h_reg * (1.f - bu) : nh_n;
        const float nc = skip_reg ? c_reg * (1.f - bu) : nc_n;
        hbuf[(size_t)par * BSZ * HCH + (size_t)brow * HCH + J] = nh;

        grid.sync();

        // ---- PhaseB: full-HC du sum (fixed order -> deterministic) ----
        const double* __restrict__ pp = part + (size_t)par * 16 * BSZ + brow;
        double s = 0.0;
        #pragma unroll
        for (int q = 0; q < 16; ++q) s += pp[q * BSZ];
        const float du_n = 1.f / (1.f + expf(-(float)(s + (double)lbv)));

        float nu, ndu;
        if (skip_reg) {
            nu  = fminf(fmaxf(u_reg + du_reg, 0.f), 1.f) * (1.f - bu);
            ndu = du_reg;
        } else {
            nu  = du_n * bu;
            ndu = du_n;
        }

        // write after sync: all PhaseA reads of seq position t are done,
        // so layer-1's in-place overwrite of its own input is race-free.
        seq_out[((size_t)t * BSZ + brow) * HCH + J] = nh;

        h_reg = nh; c_reg = nc;
        u_reg = nu; du_reg = ndu;
        skip_reg = (nu < 0.5f) ? 1 : 0;   // == (ceil(0.5/nu)-1 > 0), inf-safe
    }

    hs_out[(size_t)brow * HCH + J] = h_reg;
    cs_out[(size_t)brow * HCH + J] = c_reg;
    if (first_layer && jtile == 0 && jj == 0) {
        skipdu[brow]       = du_reg;
        skipdu[BSZ + brow] = skip_reg ? 1.f : 0.f;
    }
}

extern "C" void kernel_launch(void* const* d_in, const int* in_sizes, int n_in,
                              void* d_out, int out_size, void* d_ws, size_t ws_size,
                              hipStream_t stream)
{
    (void)in_sizes; (void)n_in; (void)out_size; (void)ws_size;

    const float* x    = (const float*)d_in[0];
    const float* Wih0 = (const float*)d_in[1];
    const float* Whh0 = (const float*)d_in[2];
    const float* bih0 = (const float*)d_in[3];
    const float* bhh0 = (const float*)d_in[4];
    const float* lw0  = (const float*)d_in[5];
    const float* lb0  = (const float*)d_in[6];
    const float* Wih1 = (const float*)d_in[7];
    const float* Whh1 = (const float*)d_in[8];
    const float* bih1 = (const float*)d_in[9];
    const float* bhh1 = (const float*)d_in[10];
    const float* lw1  = (const float*)d_in[11];
    const float* lb1  = (const float*)d_in[12];

    float* out = (float*)d_out;
    float* seq = out;                                   // (512,256,256)
    float* hs0 = out + (size_t)512 * 256 * 256;         // hs layer0
    float* hs1 = hs0 + 256 * 256;                       // hs layer1
    float* cs0 = hs1 + 256 * 256;                       // cs layer0
    float* cs1 = cs0 + 256 * 256;                       // cs layer1

    float*  hbuf   = (float*)d_ws;                                    // 512 KB
    double* part   = (double*)((char*)d_ws + (size_t)2*256*256*4);    // 64 KB
    float*  skipdu = (float*)((char*)d_ws + (size_t)2*256*256*4 + (size_t)2*16*256*8);

    int one = 1, zero = 0;

    {
        void* args[] = { (void*)&x,   (void*)&Wih0, (void*)&Whh0, (void*)&bih0,
                         (void*)&bhh0,(void*)&lw0,  (void*)&lb0,  (void*)&seq,
                         (void*)&hs0, (void*)&cs0,  (void*)&hbuf, (void*)&part,
                         (void*)&skipdu, (void*)&one };
        hipLaunchCooperativeKernel(reinterpret_cast<void*>(skiplstm_layer<128>),
                                   dim3(256), dim3(256), args, 0, stream);
    }
    {
        const float* x1 = seq;   // layer-1 input = layer-0 output, in place
        void* args[] = { (void*)&x1,  (void*)&Wih1, (void*)&Whh1, (void*)&bih1,
                         (void*)&bhh1,(void*)&lw1,  (void*)&lb1,  (void*)&seq,
                         (void*)&hs1, (void*)&cs1,  (void*)&hbuf, (void*)&part,
                         (void*)&skipdu, (void*)&zero };
        hipLaunchCooperativeKernel(reinterpret_cast<void*>(skiplstm_layer<256>),
                                   dim3(256), dim3(256), args, 0, stream);
    }
}

// Round 2
// 20987.920 us; speedup vs baseline: 1.9871x; 1.9871x over previous
//
#include <hip/hip_runtime.h>

#define TSTEPS 512
#define BSZ 256
#define HCH 256

// Grid: 256 blocks. Decode: btile = bid & 15 (group id), jtile = bid >> 4.
// All 16 blocks of a group share bid%8 -> same XCD under the round-robin
// dispatch heuristic (perf only; correctness uses agent-scope atomics).
// Each group of 16 blocks (one btile = 16 batch rows, all 256 hc) is fully
// independent of other groups: h exchange, du partial reduction, and the
// layer-1 in-place input overwrite are all row-local. So the per-step sync
// is a 16-block barrier, not a 256-block grid.sync.
//
// Per step:
//   PhaseA: gates = bias + x-part (precomputed, overlapped) + h-part (LDS W,
//           hbuf h), cell update, du partial (double) -> part[], h -> hbuf.
//   arrive(group barrier)
//   overlap: compute x-part of step t+1 (h-independent)
//   wait(group barrier)
//   PhaseB: fixed-order du sum -> du_n, scalar skip-state update, seq[t] write
//           (after barrier => layer-1 in-place input overwrite is race-free).

__device__ inline void group_arrive(unsigned* __restrict__ bar)
{
    __syncthreads();                 // all waves' global writes issued+drained
    if (threadIdx.x == 0) {
        __threadfence();             // agent-scope release (L2 writeback)
        __hip_atomic_fetch_add(bar, 1u, __ATOMIC_RELEASE, __HIP_MEMORY_SCOPE_AGENT);
    }
}

__device__ inline void group_wait(unsigned* __restrict__ bar, unsigned target)
{
    if (threadIdx.x == 0) {
        while (__hip_atomic_load(bar, __ATOMIC_RELAXED, __HIP_MEMORY_SCOPE_AGENT) < target)
            __builtin_amdgcn_s_sleep(1);
        __threadfence();             // agent-scope acquire (cache inv)
    }
    __syncthreads();
}

template<int IC>
__device__ inline void xpart_gemm(const float* __restrict__ ax,
                                  const float* __restrict__ wp0,
                                  const float* __restrict__ wp1,
                                  const float* __restrict__ wp2,
                                  const float* __restrict__ wp3,
                                  float& x0, float& x1, float& x2, float& x3)
{
    float a0 = 0.f, a1 = 0.f, a2 = 0.f, a3 = 0.f;
    #pragma unroll 4
    for (int k = 0; k < IC; k += 4) {
        const float4 a  = *(const float4*)(ax + k);
        const float4 w0 = *(const float4*)(wp0 + k);
        const float4 w1 = *(const float4*)(wp1 + k);
        const float4 w2 = *(const float4*)(wp2 + k);
        const float4 w3 = *(const float4*)(wp3 + k);
        a0 = fmaf(a.x, w0.x, a0); a0 = fmaf(a.y, w0.y, a0);
        a0 = fmaf(a.z, w0.z, a0); a0 = fmaf(a.w, w0.w, a0);
        a1 = fmaf(a.x, w1.x, a1); a1 = fmaf(a.y, w1.y, a1);
        a1 = fmaf(a.z, w1.z, a1); a1 = fmaf(a.w, w1.w, a1);
        a2 = fmaf(a.x, w2.x, a2); a2 = fmaf(a.y, w2.y, a2);
        a2 = fmaf(a.z, w2.z, a2); a2 = fmaf(a.w, w2.w, a2);
        a3 = fmaf(a.x, w3.x, a3); a3 = fmaf(a.y, w3.y, a3);
        a3 = fmaf(a.z, w3.z, a3); a3 = fmaf(a.w, w3.w, a3);
    }
    x0 = a0; x1 = a1; x2 = a2; x3 = a3;
}

template<int IC>
__global__ __launch_bounds__(256)
void skiplstm_layer(const float* __restrict__ x,      // (T, BS, IC)
                    const float* __restrict__ Wih,    // (4H, IC)
                    const float* __restrict__ Whh,    // (4H, H)
                    const float* __restrict__ bih,    // (4H)
                    const float* __restrict__ bhh,    // (4H)
                    const float* __restrict__ lw,     // (H)
                    const float* __restrict__ lb,     // (1)
                    float* __restrict__ seq_out,      // (T, BS, H)
                    float* __restrict__ hs_out,       // (BS, H)
                    float* __restrict__ cs_out,       // (BS, H)
                    float* __restrict__ hbuf,         // 2*BS*H floats (ws)
                    double* __restrict__ part,        // 2*16*BS doubles (ws)
                    float* __restrict__ skipdu,       // 2*BS floats (ws)
                    unsigned* __restrict__ cnt,       // 32 groups * 32 uints (ws)
                    int first_layer)
{
    constexpr int KH = IC + HCH;
    constexpr int KPAD = KH + 4;          // LDS bank de-conflict
    __shared__ float Wl[64][KPAD];

    const int tid   = threadIdx.x;
    const int bid   = blockIdx.x;
    const int btile = bid & 15;           // group id (same-XCD heuristic)
    const int jtile = bid >> 4;
    const int brow  = btile * 16 + (tid >> 4);
    const int jj    = tid & 15;
    const int J     = jtile * 16 + jj;

    unsigned* bar = cnt + ((first_layer ? 0 : 16) + btile) * 32;

    // ---- one-time: stage W slice into LDS (coalesced over k) ----
    for (int col = 0; col < 64; ++col) {
        const int grow = (col >> 4) * HCH + jtile * 16 + (col & 15);
        const float* __restrict__ wsrc = Wih + (size_t)grow * IC;
        for (int k = tid; k < IC; k += 256) Wl[col][k] = wsrc[k];
        const float* __restrict__ hsrc = Whh + (size_t)grow * HCH;
        for (int k = tid; k < HCH; k += 256) Wl[col][IC + k] = hsrc[k];
    }

    const float bias0 = bih[0*HCH + J] + bhh[0*HCH + J];
    const float bias1 = bih[1*HCH + J] + bhh[1*HCH + J];
    const float bias2 = bih[2*HCH + J] + bhh[2*HCH + J];
    const float bias3 = bih[3*HCH + J] + bhh[3*HCH + J];
    const float lwv = lw[J];
    const float lbv = lb[0];

    float h_reg = 0.f, c_reg = 0.f, u_reg = 1.f;
    float du_reg;
    int   skip_reg;
    if (first_layer) { du_reg = 0.f; skip_reg = 0; }
    else {
        du_reg   = skipdu[brow];
        skip_reg = (skipdu[BSZ + brow] > 0.5f) ? 1 : 0;
    }

    // h(-1) = 0 lives in parity-1 buffer (read at t=0)
    hbuf[(size_t)1 * BSZ * HCH + (size_t)brow * HCH + J] = 0.f;

    const float* __restrict__ wp0 = &Wl[0*16 + jj][0];
    const float* __restrict__ wp1 = &Wl[1*16 + jj][0];
    const float* __restrict__ wp2 = &Wl[2*16 + jj][0];
    const float* __restrict__ wp3 = &Wl[3*16 + jj][0];

    // initial barrier: Wl staged (block), h(-1) zeros visible (group)
    group_arrive(bar);
    float xn0, xn1, xn2, xn3;             // x-part of step 0, overlapped
    xpart_gemm<IC>(x + (size_t)brow * IC, wp0, wp1, wp2, wp3, xn0, xn1, xn2, xn3);
    unsigned tgt = 16;
    group_wait(bar, tgt);

    for (int t = 0; t < TSTEPS; ++t) {
        const int   par = t & 1;
        const float bu  = rintf(u_reg);   // jnp.round == rint (half-even)

        float acc0 = bias0 + xn0, acc1 = bias1 + xn1;
        float acc2 = bias2 + xn2, acc3 = bias3 + xn3;
        if (!skip_reg) {                  // skipped rows discard cell output
            const float* __restrict__ ah =
                hbuf + (size_t)(1 - par) * BSZ * HCH + (size_t)brow * HCH;
            #pragma unroll 4
            for (int k = 0; k < HCH; k += 4) {
                const float4 a  = *(const float4*)(ah + k);
                const float4 w0 = *(const float4*)(wp0 + IC + k);
                const float4 w1 = *(const float4*)(wp1 + IC + k);
                const float4 w2 = *(const float4*)(wp2 + IC + k);
                const float4 w3 = *(const float4*)(wp3 + IC + k);
                acc0 = fmaf(a.x, w0.x, acc0); acc0 = fmaf(a.y, w0.y, acc0);
                acc0 = fmaf(a.z, w0.z, acc0); acc0 = fmaf(a.w, w0.w, acc0);
                acc1 = fmaf(a.x, w1.x, acc1); acc1 = fmaf(a.y, w1.y, acc1);
                acc1 = fmaf(a.z, w1.z, acc1); acc1 = fmaf(a.w, w1.w, acc1);
                acc2 = fmaf(a.x, w2.x, acc2); acc2 = fmaf(a.y, w2.y, acc2);
                acc2 = fmaf(a.z, w2.z, acc2); acc2 = fmaf(a.w, w2.w, acc2);
                acc3 = fmaf(a.x, w3.x, acc3); acc3 = fmaf(a.y, w3.y, acc3);
                acc3 = fmaf(a.z, w3.z, acc3); acc3 = fmaf(a.w, w3.w, acc3);
            }
        }

        // ---- cell + gating (skipped rows: computed-but-discarded, finite) ----
        const float si = 1.f / (1.f + expf(-acc0));
        const float sf = 1.f / (1.f + expf(-acc1));
        const float tg = tanhf(acc2);
        const float so = 1.f / (1.f + expf(-acc3));
        const float cc = sf * c_reg + si * tg;
        const float ch = so * tanhf(cc);
        const float nc_n = cc * bu;
        const float nh_n = ch * bu;

        // du partial over this block's 16 hc (double, deterministic order)
        double p = (double)nc_n * (double)lwv;
        p += __shfl_xor(p, 1);
        p += __shfl_xor(p, 2);
        p += __shfl_xor(p, 4);
        p += __shfl_xor(p, 8);
        if (jj == 0) part[(size_t)par * 16 * BSZ + (size_t)jtile * BSZ + brow] = p;

        const float nh = skip_reg ? h_reg * (1.f - bu) : nh_n;
        const float nc = skip_reg ? c_reg * (1.f - bu) : nc_n;
        hbuf[(size_t)par * BSZ * HCH + (size_t)brow * HCH + J] = nh;

        group_arrive(bar);
        // ---- overlap: x-part of step t+1 hides under barrier skew ----
        if (t + 1 < TSTEPS)
            xpart_gemm<IC>(x + ((size_t)(t + 1) * BSZ + brow) * IC,
                           wp0, wp1, wp2, wp3, xn0, xn1, xn2, xn3);
        tgt += 16;
        group_wait(bar, tgt);

        // ---- PhaseB: full-HC du sum (fixed order -> deterministic) ----
        const double* __restrict__ pp = part + (size_t)par * 16 * BSZ + brow;
        double s = 0.0;
        #pragma unroll
        for (int q = 0; q < 16; ++q) s += pp[q * BSZ];
        const float du_n = 1.f / (1.f + expf(-(float)(s + (double)lbv)));

        float nu, ndu;
        if (skip_reg) {
            nu  = fminf(fmaxf(u_reg + du_reg, 0.f), 1.f) * (1.f - bu);
            ndu = du_reg;
        } else {
            nu  = du_n * bu;
            ndu = du_n;
        }

        // after barrier: all group blocks read x[t], so layer-1's in-place
        // overwrite of its own input row-block is race-free.
        seq_out[((size_t)t * BSZ + brow) * HCH + J] = nh;

        h_reg = nh; c_reg = nc;
        u_reg = nu; du_reg = ndu;
        skip_reg = (nu < 0.5f) ? 1 : 0;   // == (ceil(0.5/nu)-1 > 0), inf-safe
    }

    hs_out[(size_t)brow * HCH + J] = h_reg;
    cs_out[(size_t)brow * HCH + J] = c_reg;
    if (first_layer && jtile == 0 && jj == 0) {
        skipdu[brow]       = du_reg;
        skipdu[BSZ + brow] = skip_reg ? 1.f : 0.f;
    }
}

extern "C" void kernel_launch(void* const* d_in, const int* in_sizes, int n_in,
                              void* d_out, int out_size, void* d_ws, size_t ws_size,
                              hipStream_t stream)
{
    (void)in_sizes; (void)n_in; (void)out_size; (void)ws_size;

    const float* x    = (const float*)d_in[0];
    const float* Wih0 = (const float*)d_in[1];
    const float* Whh0 = (const float*)d_in[2];
    const float* bih0 = (const float*)d_in[3];
    const float* bhh0 = (const float*)d_in[4];
    const float* lw0  = (const float*)d_in[5];
    const float* lb0  = (const float*)d_in[6];
    const float* Wih1 = (const float*)d_in[7];
    const float* Whh1 = (const float*)d_in[8];
    const float* bih1 = (const float*)d_in[9];
    const float* bhh1 = (const float*)d_in[10];
    const float* lw1  = (const float*)d_in[11];
    const float* lb1  = (const float*)d_in[12];

    float* out = (float*)d_out;
    float* seq = out;                                   // (512,256,256)
    float* hs0 = out + (size_t)512 * 256 * 256;
    float* hs1 = hs0 + 256 * 256;
    float* cs0 = hs1 + 256 * 256;
    float* cs1 = cs0 + 256 * 256;

    char* ws = (char*)d_ws;
    float*    hbuf   = (float*)   ws;                              // 524288 B
    double*   part   = (double*) (ws + 524288);                    //  65536 B
    float*    skipdu = (float*)  (ws + 524288 + 65536);            //   2048 B
    unsigned* cnt    = (unsigned*)(ws + 524288 + 65536 + 2048);    //   4096 B

    hipMemsetAsync(cnt, 0, 32 * 32 * sizeof(unsigned), stream);

    int one = 1, zero = 0;

    {
        void* args[] = { (void*)&x,   (void*)&Wih0, (void*)&Whh0, (void*)&bih0,
                         (void*)&bhh0,(void*)&lw0,  (void*)&lb0,  (void*)&seq,
                         (void*)&hs0, (void*)&cs0,  (void*)&hbuf, (void*)&part,
                         (void*)&skipdu, (void*)&cnt, (void*)&one };
        hipLaunchCooperativeKernel(reinterpret_cast<void*>(skiplstm_layer<128>),
                                   dim3(256), dim3(256), args, 0, stream);
    }
    {
        const float* x1 = seq;   // layer-1 input = layer-0 output, in place
        void* args[] = { (void*)&x1,  (void*)&Wih1, (void*)&Whh1, (void*)&bih1,
                         (void*)&bhh1,(void*)&lw1,  (void*)&lb1,  (void*)&seq,
                         (void*)&hs1, (void*)&cs1,  (void*)&hbuf, (void*)&part,
                         (void*)&skipdu, (void*)&cnt, (void*)&zero };
        hipLaunchCooperativeKernel(reinterpret_cast<void*>(skiplstm_layer<256>),
                                   dim3(256), dim3(256), args, 0, stream);
    }
}

// Round 3
// 17766.158 us; speedup vs baseline: 2.3475x; 1.1813x over previous
//
#include <hip/hip_runtime.h>

#define TSTEPS 512
#define BSZ 256
#define HCH 256

// Decomposition: 256 blocks = 16 groups (btile = bid & 15) x 16 jtile (bid >> 4).
// Group = one btile (16 batch rows) x all 256 hc; groups never communicate.
// Per step, one group barrier:
//   phaseA: gates = bias + x-part(prefetched) + h-part (W in LDS, h-slab in LDS),
//           cell, du-partial -> part[], own h-tile -> hbuf[par].
//   arrive: release fence (waitcnt + wbl2; L2 kept ~clean via nt seq stores)
//           + relaxed flag store (own flag word, no RMW contention).
//   overlap: x-part of step t+1 (h-independent); layer0 also stores seq[t] (nt).
//   wait:   16 lanes poll the group's 16 contiguous flags; acquire fence (inv).
//   phaseB: coalesced part load + fp64 shfl-xor tree (bit-identical across all
//           replicas -> skip decisions stay coherent), u/du/skip update,
//           layer1 seq[t] store (post-barrier => in-place input is race-free),
//           stage h(t) slab -> LDS for step t+1.

__device__ __forceinline__ float sigmoidf_(float v) { return 1.f / (1.f + expf(-v)); }

template<int IC>
__device__ __forceinline__ void xpart_gemm(const float* __restrict__ ax,
                                           const float* __restrict__ wp0,
                                           const float* __restrict__ wp1,
                                           const float* __restrict__ wp2,
                                           const float* __restrict__ wp3,
                                           float& x0, float& x1, float& x2, float& x3)
{
    float a0 = 0.f, a1 = 0.f, a2 = 0.f, a3 = 0.f;
    #pragma unroll 4
    for (int k = 0; k < IC; k += 4) {
        const float4 a  = *(const float4*)(ax + k);
        const float4 w0 = *(const float4*)(wp0 + k);
        const float4 w1 = *(const float4*)(wp1 + k);
        const float4 w2 = *(const float4*)(wp2 + k);
        const float4 w3 = *(const float4*)(wp3 + k);
        a0 = fmaf(a.x, w0.x, a0); a0 = fmaf(a.y, w0.y, a0);
        a0 = fmaf(a.z, w0.z, a0); a0 = fmaf(a.w, w0.w, a0);
        a1 = fmaf(a.x, w1.x, a1); a1 = fmaf(a.y, w1.y, a1);
        a1 = fmaf(a.z, w1.z, a1); a1 = fmaf(a.w, w1.w, a1);
        a2 = fmaf(a.x, w2.x, a2); a2 = fmaf(a.y, w2.y, a2);
        a2 = fmaf(a.z, w2.z, a2); a2 = fmaf(a.w, w2.w, a2);
        a3 = fmaf(a.x, w3.x, a3); a3 = fmaf(a.y, w3.y, a3);
        a3 = fmaf(a.z, w3.z, a3); a3 = fmaf(a.w, w3.w, a3);
    }
    x0 = a0; x1 = a1; x2 = a2; x3 = a3;
}

template<int IC>
__global__ __launch_bounds__(256)
void skiplstm_layer(const float* __restrict__ x,      // (T, BS, IC)
                    const float* __restrict__ Wih,    // (4H, IC)
                    const float* __restrict__ Whh,    // (4H, H)
                    const float* __restrict__ bih,    // (4H)
                    const float* __restrict__ bhh,    // (4H)
                    const float* __restrict__ lw,     // (H)
                    const float* __restrict__ lb,     // (1)
                    float* __restrict__ seq_out,      // (T, BS, H)
                    float* __restrict__ hs_out,       // (BS, H)
                    float* __restrict__ cs_out,       // (BS, H)
                    float* __restrict__ hbuf,         // [2][16][16][256] f32 (ws)
                    double* __restrict__ part,        // [2][16][16][16] f64 (ws)
                    float* __restrict__ skipdu,       // [2][256] f32 (ws)
                    unsigned* __restrict__ flags)     // [2][256] u32 (ws)
{
    constexpr bool FIRST = (IC == 128);
    constexpr int KH = IC + HCH;
    constexpr int KPAD = KH + 4;          // LDS bank de-conflict for W
    __shared__ float Wl[64][KPAD];
    __shared__ float Asl[16][260];        // h-slab, padded (4-row bank spread)

    const int tid   = threadIdx.x;
    const int bid   = blockIdx.x;
    const int btile = bid & 15;           // group id
    const int jtile = bid >> 4;
    const int R     = tid >> 4;           // row within tile
    const int jj    = tid & 15;
    const int J     = jtile * 16 + jj;
    const int brow  = btile * 16 + R;

    unsigned* gflags = flags + (FIRST ? 0 : 256) + btile * 16; // 16 contiguous
    unsigned* myflag = gflags + jtile;

    // ---- one-time: stage W slice into LDS (coalesced over k) ----
    for (int col = 0; col < 64; ++col) {
        const int grow = (col >> 4) * HCH + jtile * 16 + (col & 15);
        const float* __restrict__ wsrc = Wih + (size_t)grow * IC;
        for (int k = tid; k < IC; k += 256) Wl[col][k] = wsrc[k];
        const float* __restrict__ hsrc = Whh + (size_t)grow * HCH;
        for (int k = tid; k < HCH; k += 256) Wl[col][IC + k] = hsrc[k];
    }

    const float bias0 = bih[0*HCH + J] + bhh[0*HCH + J];
    const float bias1 = bih[1*HCH + J] + bhh[1*HCH + J];
    const float bias2 = bih[2*HCH + J] + bhh[2*HCH + J];
    const float bias3 = bih[3*HCH + J] + bhh[3*HCH + J];
    const float lwv = lw[J];
    const float lbv = lb[0];

    float h_reg = 0.f, c_reg = 0.f, u_reg = 1.f;
    float du_reg;
    int   skip_reg;
    if (FIRST) { du_reg = 0.f; skip_reg = 0; }
    else {
        du_reg   = skipdu[brow];
        skip_reg = (skipdu[BSZ + brow] > 0.5f) ? 1 : 0;
    }

    // h(-1) = 0 in parity-1 slab (staged after initial barrier)
    hbuf[(((size_t)1 * 16 + btile) * 16 + R) * 256 + J] = 0.f;

    const float* __restrict__ wp0 = &Wl[0*16 + jj][0];
    const float* __restrict__ wp1 = &Wl[1*16 + jj][0];
    const float* __restrict__ wp2 = &Wl[2*16 + jj][0];
    const float* __restrict__ wp3 = &Wl[3*16 + jj][0];

    // ---- initial arrive: zeros + (nothing else) must be group-visible ----
    asm volatile("s_waitcnt vmcnt(0) lgkmcnt(0)" ::: "memory");
    __syncthreads();
    if (tid == 0) {
        __builtin_amdgcn_fence(__ATOMIC_RELEASE, "agent");
        __hip_atomic_store(myflag, 1u, __ATOMIC_RELAXED, __HIP_MEMORY_SCOPE_AGENT);
    }
    float xn0, xn1, xn2, xn3;             // x-part of step 0, overlapped
    xpart_gemm<IC>(x + (size_t)brow * IC, wp0, wp1, wp2, wp3, xn0, xn1, xn2, xn3);
    if (tid < 16) {
        while (__hip_atomic_load(gflags + tid, __ATOMIC_RELAXED,
                                 __HIP_MEMORY_SCOPE_AGENT) < 1u)
            __builtin_amdgcn_s_sleep(1);
    }
    __syncthreads();
    __builtin_amdgcn_fence(__ATOMIC_ACQUIRE, "agent");

    // ---- stage h(-1) zeros into LDS slab ----
    {
        const float4* __restrict__ src =
            (const float4*)(hbuf + (((size_t)1 * 16 + btile) * 16) * 256);
        #pragma unroll
        for (int i = 0; i < 4; ++i) {
            const int f = tid + i * 256;          // float4 index within slab
            const float4 v = src[f];
            *(float4*)(&Asl[f >> 6][(f & 63) * 4]) = v;
        }
    }
    __syncthreads();

    for (int t = 0; t < TSTEPS; ++t) {
        const int   par = t & 1;
        const float bu  = rintf(u_reg);   // jnp.round == rint (half-even)

        float acc0 = bias0 + xn0, acc1 = bias1 + xn1;
        float acc2 = bias2 + xn2, acc3 = bias3 + xn3;
        if (!skip_reg) {                  // skipped rows discard cell output
            const float* __restrict__ ah = &Asl[R][0];
            #pragma unroll 4
            for (int k = 0; k < HCH; k += 4) {
                const float4 a  = *(const float4*)(ah + k);
                const float4 w0 = *(const float4*)(wp0 + IC + k);
                const float4 w1 = *(const float4*)(wp1 + IC + k);
                const float4 w2 = *(const float4*)(wp2 + IC + k);
                const float4 w3 = *(const float4*)(wp3 + IC + k);
                acc0 = fmaf(a.x, w0.x, acc0); acc0 = fmaf(a.y, w0.y, acc0);
                acc0 = fmaf(a.z, w0.z, acc0); acc0 = fmaf(a.w, w0.w, acc0);
                acc1 = fmaf(a.x, w1.x, acc1); acc1 = fmaf(a.y, w1.y, acc1);
                acc1 = fmaf(a.z, w1.z, acc1); acc1 = fmaf(a.w, w1.w, acc1);
                acc2 = fmaf(a.x, w2.x, acc2); acc2 = fmaf(a.y, w2.y, acc2);
                acc2 = fmaf(a.z, w2.z, acc2); acc2 = fmaf(a.w, w2.w, acc2);
                acc3 = fmaf(a.x, w3.x, acc3); acc3 = fmaf(a.y, w3.y, acc3);
                acc3 = fmaf(a.z, w3.z, acc3); acc3 = fmaf(a.w, w3.w, acc3);
            }
        }

        // ---- cell + gating (skipped rows: computed-but-discarded, finite) ----
        const float si = sigmoidf_(acc0);
        const float sf = sigmoidf_(acc1);
        const float tg = tanhf(acc2);
        const float so = sigmoidf_(acc3);
        const float cc = sf * c_reg + si * tg;
        const float ch = so * tanhf(cc);
        const float nc_n = cc * bu;
        const float nh_n = ch * bu;

        // du partial over this block's 16 hc (fp64 shfl tree, deterministic)
        double p = (double)nc_n * (double)lwv;
        p += __shfl_xor(p, 1);
        p += __shfl_xor(p, 2);
        p += __shfl_xor(p, 4);
        p += __shfl_xor(p, 8);
        if (jj == jtile)
            part[((size_t)par * 16 + btile) * 256 + R * 16 + jtile] = p;

        const float nh = skip_reg ? h_reg * (1.f - bu) : nh_n;
        const float nc = skip_reg ? c_reg * (1.f - bu) : nc_n;
        hbuf[(((size_t)par * 16 + btile) * 16 + R) * 256 + J] = nh;

        // ---- arrive ----
        asm volatile("s_waitcnt vmcnt(0) lgkmcnt(0)" ::: "memory");
        __syncthreads();
        if (tid == 0) {
            __builtin_amdgcn_fence(__ATOMIC_RELEASE, "agent");
            __hip_atomic_store(myflag, (unsigned)(t + 2), __ATOMIC_RELAXED,
                               __HIP_MEMORY_SCOPE_AGENT);
        }

        // ---- overlap window: x-part of t+1; layer0's seq store (safe early) ----
        if (FIRST)
            __builtin_nontemporal_store(nh, seq_out + ((size_t)t * BSZ + brow) * HCH + J);
        if (t + 1 < TSTEPS)
            xpart_gemm<IC>(x + ((size_t)(t + 1) * BSZ + brow) * IC,
                           wp0, wp1, wp2, wp3, xn0, xn1, xn2, xn3);

        // ---- wait ----
        if (tid < 16) {
            while (__hip_atomic_load(gflags + tid, __ATOMIC_RELAXED,
                                     __HIP_MEMORY_SCOPE_AGENT) < (unsigned)(t + 2))
                __builtin_amdgcn_s_sleep(1);
        }
        __syncthreads();
        __builtin_amdgcn_fence(__ATOMIC_ACQUIRE, "agent");

        // ---- phaseB: du sum (coalesced load + fp64 xor-tree over q=jj) ----
        const double* __restrict__ pp = part + ((size_t)par * 16 + btile) * 256;
        double s = pp[tid];               // == [R][q] for this lane
        s += __shfl_xor(s, 1);
        s += __shfl_xor(s, 2);
        s += __shfl_xor(s, 4);
        s += __shfl_xor(s, 8);            // all 16 q-lanes hold row sum
        const float du_n = sigmoidf_((float)(s + (double)lbv));

        float nu, ndu;
        if (skip_reg) {
            nu  = fminf(fmaxf(u_reg + du_reg, 0.f), 1.f) * (1.f - bu);
            ndu = du_reg;
        } else {
            nu  = du_n * bu;
            ndu = du_n;
        }

        if (!FIRST)   // post-barrier: in-place overwrite of own input is race-free
            __builtin_nontemporal_store(nh, seq_out + ((size_t)t * BSZ + brow) * HCH + J);

        // ---- stage h(t) slab -> LDS for step t+1 ----
        if (t + 1 < TSTEPS) {
            const float4* __restrict__ src =
                (const float4*)(hbuf + (((size_t)par * 16 + btile) * 16) * 256);
            float4 v0, v1, v2, v3;
            v0 = src[tid];           v1 = src[tid + 256];
            v2 = src[tid + 512];     v3 = src[tid + 768];
            *(float4*)(&Asl[(tid      ) >> 6][((tid      ) & 63) * 4]) = v0;
            *(float4*)(&Asl[(tid + 256) >> 6][((tid + 256) & 63) * 4]) = v1;
            *(float4*)(&Asl[(tid + 512) >> 6][((tid + 512) & 63) * 4]) = v2;
            *(float4*)(&Asl[(tid + 768) >> 6][((tid + 768) & 63) * 4]) = v3;
        }
        __syncthreads();   // slab ready before next phaseA reads

        h_reg = nh; c_reg = nc;
        u_reg = nu; du_reg = ndu;
        skip_reg = (nu < 0.5f) ? 1 : 0;   // == (ceil(0.5/nu)-1 > 0), inf-safe
    }

    hs_out[(size_t)brow * HCH + J] = h_reg;
    cs_out[(size_t)brow * HCH + J] = c_reg;
    if (FIRST && jtile == 0 && jj == 0) {
        skipdu[brow]       = du_reg;
        skipdu[BSZ + brow] = skip_reg ? 1.f : 0.f;
    }
}

extern "C" void kernel_launch(void* const* d_in, const int* in_sizes, int n_in,
                              void* d_out, int out_size, void* d_ws, size_t ws_size,
                              hipStream_t stream)
{
    (void)in_sizes; (void)n_in; (void)out_size; (void)ws_size;

    const float* x    = (const float*)d_in[0];
    const float* Wih0 = (const float*)d_in[1];
    const float* Whh0 = (const float*)d_in[2];
    const float* bih0 = (const float*)d_in[3];
    const float* bhh0 = (const float*)d_in[4];
    const float* lw0  = (const float*)d_in[5];
    const float* lb0  = (const float*)d_in[6];
    const float* Wih1 = (const float*)d_in[7];
    const float* Whh1 = (const float*)d_in[8];
    const float* bih1 = (const float*)d_in[9];
    const float* bhh1 = (const float*)d_in[10];
    const float* lw1  = (const float*)d_in[11];
    const float* lb1  = (const float*)d_in[12];

    float* out = (float*)d_out;
    float* seq = out;                                   // (512,256,256)
    float* hs0 = out + (size_t)512 * 256 * 256;
    float* hs1 = hs0 + 256 * 256;
    float* cs0 = hs1 + 256 * 256;
    float* cs1 = cs0 + 256 * 256;

    char* ws = (char*)d_ws;
    float*    hbuf   = (float*)    ws;                               // 524288 B
    double*   part   = (double*)  (ws + 524288);                     //  65536 B
    float*    skipdu = (float*)   (ws + 524288 + 65536);             //   2048 B
    unsigned* flags  = (unsigned*)(ws + 524288 + 65536 + 2048);      //   2048 B

    hipMemsetAsync(flags, 0, 2 * 256 * sizeof(unsigned), stream);

    {
        void* args[] = { (void*)&x,   (void*)&Wih0, (void*)&Whh0, (void*)&bih0,
                         (void*)&bhh0,(void*)&lw0,  (void*)&lb0,  (void*)&seq,
                         (void*)&hs0, (void*)&cs0,  (void*)&hbuf, (void*)&part,
                         (void*)&skipdu, (void*)&flags };
        hipLaunchCooperativeKernel(reinterpret_cast<void*>(skiplstm_layer<128>),
                                   dim3(256), dim3(256), args, 0, stream);
    }
    {
        const float* x1 = seq;   // layer-1 input = layer-0 output, in place
        void* args[] = { (void*)&x1,  (void*)&Wih1, (void*)&Whh1, (void*)&bih1,
                         (void*)&bhh1,(void*)&lw1,  (void*)&lb1,  (void*)&seq,
                         (void*)&hs1, (void*)&cs1,  (void*)&hbuf, (void*)&part,
                         (void*)&skipdu, (void*)&flags };
        hipLaunchCooperativeKernel(reinterpret_cast<void*>(skiplstm_layer<256>),
                                   dim3(256), dim3(256), args, 0, stream);
    }
}